// Round 1
// baseline (921.848 us; speedup 1.0000x reference)
//
#include <hip/hip_runtime.h>
#include <hip/hip_bf16.h>

#define BB   4096
#define SS   512
#define NCOV 10
#define NG   256    // 4*HID gate columns
#define BT   16     // batch rows per workgroup
#define XSTR 104    // padded shorts per X row (96 K-slots + 8 pad -> 208B = 52 banks)
#define TGT_STR 516 // padded target row stride (f32)
#define SB_STR  260 // padded sbias row stride (f32)

typedef __bf16 bf16_t;
typedef bf16_t bf16x8 __attribute__((ext_vector_type(8)));
typedef float  f32x4  __attribute__((ext_vector_type(4)));

__device__ __forceinline__ unsigned short f2bf(float x) {
    union { float f; unsigned u; } q{x};
    unsigned r = (q.u + 0x7fffu + ((q.u >> 16) & 1u)) >> 16;
    return (unsigned short)r;
}
__device__ __forceinline__ float bf2f(unsigned short s) {
    union { unsigned u; float f; } q{((unsigned)s) << 16};
    return q.f;
}
__device__ __forceinline__ float sigmoid_(float x) { return 1.0f / (1.0f + __expf(-x)); }
__device__ __forceinline__ float tanh_(float x)    { return 2.0f / (1.0f + __expf(-2.0f * x)) - 1.0f; }
__device__ __forceinline__ float softplus_(float x){ return x > 20.0f ? x : __logf(1.0f + __expf(x)); }

// X K-slot layout (96 slots, must match W row layout in b-fragments):
//   k=0      : prev            (weight w_ih row 0)
//   k=1..10  : cov[0..9]       (w_ih rows 1..10)
//   k=11     : prev bf16 residual (w_ih row 0 again -> ~fp24 effective prev)
//   k=12..75 : h[0..63]        (w_hh rows 0..63)
//   k=76..95 : zero pad        (W rows = 0)
__global__ __launch_bounds__(256, 1)
void deepar_kernel(const float* __restrict__ target, const float* __restrict__ cov,
                   const int* __restrict__ cats, const float* __restrict__ scale,
                   const float* __restrict__ emb0, const float* __restrict__ emb1,
                   const float* __restrict__ emb2, const float* __restrict__ emb3,
                   const float* __restrict__ w_ih, const float* __restrict__ w_hh,
                   const float* __restrict__ bias, const float* __restrict__ w_out,
                   const float* __restrict__ b_out, float* __restrict__ out)
{
    __shared__ float tgt[BT * TGT_STR];
    __shared__ float sbias[BT * SB_STR];
    __shared__ float sx[BT * 68];                // static_x: 64 emb + log1p(scale)
    __shared__ __attribute__((aligned(16))) unsigned short xbuf[2][BT * XSTR];
    __shared__ float inv_s[BT], scl_s[BT];

    const int tid  = threadIdx.x;
    const int b0   = blockIdx.x * BT;
    const int lane = tid & 63;
    const int wv   = tid >> 6;
    const int qd   = lane >> 4;     // quad 0..3
    const int ln   = lane & 15;

    // ---------------- phase 0: one-time setup ----------------
    for (int idx = tid; idx < BT * SS; idx += 256) {
        int r = idx >> 9, t = idx & (SS - 1);
        tgt[r * TGT_STR + t] = target[(b0 + r) * SS + t];
    }
    if (tid < BT) {
        float s = scale[b0 + tid];
        scl_s[tid] = s;
        inv_s[tid] = 1.0f / fmaxf(s, 1e-4f);
        sx[tid * 68 + 64] = log1pf(s);
    }
    if (tid < BT * 4) {
        int r = tid >> 2, e = tid & 3;
        int c = cats[(b0 + r) * 4 + e];
        const float* eb = (e == 0 ? emb0 : e == 1 ? emb1 : e == 2 ? emb2 : emb3);
        for (int j = 0; j < 16; ++j) sx[r * 68 + e * 16 + j] = eb[c * 16 + j];
    }
    for (int idx = tid; idx < 2 * BT * XSTR; idx += 256)
        ((unsigned short*)xbuf)[idx] = 0;       // zeros pads, h0, prev0
    __syncthreads();

    // stage cov_0 into xbuf[0]
    if (tid < BT * NCOV) {
        int r = tid / NCOV, k = tid % NCOV;
        xbuf[0][r * XSTR + 1 + k] = f2bf(cov[((b0 + r) * SS + 0) * NCOV + k]);
    }

    // sbias[r][j] = bias[j] + sum_k sx[r][k] * w_ih[11+k][j]   (k = 0..64)
    {
        float bj = bias[tid];
        float acc[BT];
        #pragma unroll
        for (int r = 0; r < BT; ++r) acc[r] = bj;
        for (int k = 0; k < 65; ++k) {
            float w = w_ih[(11 + k) * NG + tid];
            #pragma unroll
            for (int r = 0; r < BT; ++r) acc[r] += sx[r * 68 + k] * w;
        }
        #pragma unroll
        for (int r = 0; r < BT; ++r) sbias[r * SB_STR + tid] = acc[r];
    }
    __syncthreads();

    // ---------------- register-resident weights ----------------
    bf16x8 bfrag[4][3];   // [tile-of-this-wave][K-chunk]
    f32x4  sbf[4];        // sbias C-operand fragments
    #pragma unroll
    for (int ti = 0; ti < 4; ++ti) {
        int tile = wv + 4 * ti;          // this wave's tiles: gate ti, units 16*wv..16*wv+15
        int n = ln + 16 * tile;
        #pragma unroll
        for (int c = 0; c < 3; ++c) {
            #pragma unroll
            for (int j = 0; j < 8; ++j) {
                int k = qd * 8 + 32 * c + j;
                float w;
                if (k == 0)       w = w_ih[n];
                else if (k <= 10) w = w_ih[k * NG + n];
                else if (k == 11) w = w_ih[n];                // prev residual row
                else if (k <= 75) w = w_hh[(k - 12) * NG + n];
                else              w = 0.0f;
                bfrag[ti][c][j] = (bf16_t)w;
            }
        }
        #pragma unroll
        for (int r = 0; r < 4; ++r)
            sbf[ti][r] = sbias[(qd * 4 + r) * SB_STR + n];
    }

    // output-head thread mapping: (row, out_idx, k-group-of-8)
    const int prow = tid >> 4, po = (tid >> 3) & 1, pkg = tid & 7;
    float wo[8];
    #pragma unroll
    for (int j = 0; j < 8; ++j) wo[j] = w_out[(pkg * 8 + j) * 2 + po];
    const float bo   = b_out[po];
    const float pscl = (po == 0) ? scl_s[prow] : 1.0f;

    auto project = [&](int cur, int tout) {
        const unsigned short* xb = &xbuf[cur][prow * XSTR + 12 + pkg * 8];
        float p = 0.0f;
        #pragma unroll
        for (int j = 0; j < 8; ++j) p += bf2f(xb[j]) * wo[j];
        p += __shfl_xor(p, 1);
        p += __shfl_xor(p, 2);
        p += __shfl_xor(p, 4);
        if (pkg == 0) {
            float sp = softplus_(p + bo) + 1e-4f;
            out[(po ? (BB * SS) : 0) + (b0 + prow) * SS + tout] = sp * pscl;
        }
    };

    float cst[4] = {0.0f, 0.0f, 0.0f, 0.0f};

    // ---------------- time loop ----------------
    for (int t = 0; t < SS; ++t) {
        const int cur = t & 1, nxt = cur ^ 1;
        __syncthreads();   // xbuf[cur] complete (h from t-1, prev/cov staged at t-1)

        // output head for step t-1 (h_{t-1} sits in xbuf[cur] k=12..75)
        if (t > 0) project(cur, t - 1);

        // stage next step's prev/cov (issue global loads early)
        float stage_val = 0.0f;
        int   do_stage = 0, srow = 0, sk = 0;
        if (t + 1 < SS && tid < BT * 12) {
            srow = tid / 12; sk = tid % 12; do_stage = 1;
            if (sk == 0 || sk == 11) {
                float pv = tgt[srow * TGT_STR + t] * inv_s[srow];
                stage_val = (sk == 0) ? pv : (pv - bf2f(f2bf(pv)));
            } else {
                stage_val = cov[((b0 + srow) * SS + (t + 1)) * NCOV + (sk - 1)];
            }
        }

        // A fragments from xbuf[cur]
        const unsigned short* xr = &xbuf[cur][ln * XSTR + qd * 8];
        bf16x8 a0 = *(const bf16x8*)(xr);
        bf16x8 a1 = *(const bf16x8*)(xr + 32);
        bf16x8 a2 = *(const bf16x8*)(xr + 64);

        // gates = X @ W + sbias
        f32x4 acc0 = __builtin_amdgcn_mfma_f32_16x16x32_bf16(a0, bfrag[0][0], sbf[0], 0, 0, 0);
        f32x4 acc1 = __builtin_amdgcn_mfma_f32_16x16x32_bf16(a0, bfrag[1][0], sbf[1], 0, 0, 0);
        f32x4 acc2 = __builtin_amdgcn_mfma_f32_16x16x32_bf16(a0, bfrag[2][0], sbf[2], 0, 0, 0);
        f32x4 acc3 = __builtin_amdgcn_mfma_f32_16x16x32_bf16(a0, bfrag[3][0], sbf[3], 0, 0, 0);
        acc0 = __builtin_amdgcn_mfma_f32_16x16x32_bf16(a1, bfrag[0][1], acc0, 0, 0, 0);
        acc1 = __builtin_amdgcn_mfma_f32_16x16x32_bf16(a1, bfrag[1][1], acc1, 0, 0, 0);
        acc2 = __builtin_amdgcn_mfma_f32_16x16x32_bf16(a1, bfrag[2][1], acc2, 0, 0, 0);
        acc3 = __builtin_amdgcn_mfma_f32_16x16x32_bf16(a1, bfrag[3][1], acc3, 0, 0, 0);
        acc0 = __builtin_amdgcn_mfma_f32_16x16x32_bf16(a2, bfrag[0][2], acc0, 0, 0, 0);
        acc1 = __builtin_amdgcn_mfma_f32_16x16x32_bf16(a2, bfrag[1][2], acc1, 0, 0, 0);
        acc2 = __builtin_amdgcn_mfma_f32_16x16x32_bf16(a2, bfrag[2][2], acc2, 0, 0, 0);
        acc3 = __builtin_amdgcn_mfma_f32_16x16x32_bf16(a2, bfrag[3][2], acc3, 0, 0, 0);

        // write next-step prev/cov
        if (do_stage) xbuf[nxt][srow * XSTR + sk] = f2bf(stage_val);

        // lane-local LSTM cell: lane holds i,f,g,o for unit u = 16*wv + ln, rows qd*4+r
        #pragma unroll
        for (int r = 0; r < 4; ++r) {
            float ig = sigmoid_(acc0[r]);
            float fg = sigmoid_(acc1[r]);
            float gg = tanh_(acc2[r]);
            float og = sigmoid_(acc3[r]);
            float c  = fg * cst[r] + ig * gg;
            cst[r] = c;
            float h  = og * tanh_(c);
            xbuf[nxt][(qd * 4 + r) * XSTR + 12 + 16 * wv + ln] = f2bf(h);
        }
    }

    // final output head for t = 511 (h_511 was written into xbuf[0])
    __syncthreads();
    project(0, SS - 1);
}

extern "C" void kernel_launch(void* const* d_in, const int* in_sizes, int n_in,
                              void* d_out, int out_size, void* d_ws, size_t ws_size,
                              hipStream_t stream) {
    deepar_kernel<<<BB / BT, 256, 0, stream>>>(
        (const float*)d_in[0], (const float*)d_in[1], (const int*)d_in[2],
        (const float*)d_in[3], (const float*)d_in[4], (const float*)d_in[5],
        (const float*)d_in[6], (const float*)d_in[7], (const float*)d_in[8],
        (const float*)d_in[9], (const float*)d_in[10], (const float*)d_in[11],
        (const float*)d_in[12], (float*)d_out);
}